// Round 1
// 1570.677 us; speedup vs baseline: 1.1421x; 1.1421x over previous
//
#include <hip/hip_runtime.h>
#include <math.h>

// B=256, T=2048, D=64, U=128, 4U=512, COND=32
namespace {
constexpr int kB    = 256;
constexpr int kT    = 2048;
constexpr int kD    = 64;
constexpr int kU    = 128;
constexpr int kCOND = 32;
constexpr int kCH   = 16;   // x-chunk: timesteps staged per bulk prefetch
}

typedef _Float16 f16x8 __attribute__((ext_vector_type(8)));
typedef float    f32x4 __attribute__((ext_vector_type(4)));

__device__ __forceinline__ float sig_(float z) {
    return 1.0f / (1.0f + __expf(-z));
}
__device__ __forceinline__ float tanh_(float z) {
    float ez = __expf(-2.0f * fabsf(z));
    float t  = (1.0f - ez) / (1.0f + ez);
    return copysignf(t, z);
}
// pin a 16B fragment so the allocator cannot rematerialize its global loads
__device__ __forceinline__ void pin4_(f16x8& w) {
    f32x4 t = __builtin_bit_cast(f32x4, w);
    asm volatile("" : "+v"(t));
    w = __builtin_bit_cast(f16x8, t);
}

// One WG (512 thr = 8 waves) per batch element, persistent over T steps.
// MFMA m-broadcast trick: A-operand = activations a[192]=[x(64);h(128)]
// replicated over all 16 M-rows; B-operand = weights in registers (m91
// fragment rule), wave w owns N-tiles {w,w+8,w+16,w+24} so all four gate
// preacts for u = 16w + (lane&15) land in-lane.
//
// This revision removes the two per-step global-latency serializers:
//  (a) x is staged in 16-step chunks into a double-buffered LDS ring;
//      the float2 loads for chunk k+1 are ISSUED at the first step of
//      chunk k and only converted+written to LDS at its last step
//      (prefetch distance ~15 steps, HBM latency fully hidden).
//  (b) the in-loop __syncthreads() (which drains vmcnt(0) and would
//      re-serialize the prefetch) is replaced by a raw
//      "s_waitcnt lgkmcnt(0); s_barrier" — LDS-only wait, prefetch
//      stays in flight across step barriers.
__global__ __launch_bounds__(512, 2)
void lstm_mfma(const float* __restrict__ x,     // [B,T,D]
               const float* __restrict__ cond,  // [B,COND]
               const float* __restrict__ Wc,    // [COND,U]
               const float* __restrict__ bc,    // [U]
               const float* __restrict__ Wk,    // [D,4U]
               const float* __restrict__ Uk,    // [U,4U]
               const float* __restrict__ bias,  // [4U]
               float* __restrict__ out) {       // [B,U]
    const int b    = blockIdx.x;
    const int tid  = threadIdx.x;
    const int lane = tid & 63;
    const int w    = tid >> 6;     // wave 0..7
    const int q    = lane >> 4;    // quad 0..3
    const int c    = lane & 15;
    const int u    = 16 * w + c;   // this lane's state element

    __shared__ __align__(16) _Float16 hbuf[2][kU];     // h double-buffer
    __shared__ __align__(16) _Float16 xs[2][kCH][kD];  // x chunk ring (f16)

    // ---- B-frags: 4 tiles x 6 K-chunks, k = 32*kc + 8*q + j, col = 16t + c ----
    f16x8 wfrag[4][6];
    float btile[4];
#pragma unroll
    for (int jt = 0; jt < 4; ++jt) {
        const int t   = w + 8 * jt;          // tile; jt = gate index (i,f,c~,o)
        const int col = 16 * t + c;
#pragma unroll
        for (int kc = 0; kc < 6; ++kc) {
            f16x8 f;
#pragma unroll
            for (int j = 0; j < 8; ++j) {
                const int k = 32 * kc + 8 * q + j;
                const float v = (k < kD) ? Wk[k * 512 + col]
                                         : Uk[(k - kD) * 512 + col];
                f[j] = (_Float16)v;
            }
            wfrag[jt][kc] = f;
        }
        btile[jt] = bias[col];
    }
#pragma unroll
    for (int jt = 0; jt < 4; ++jt)
#pragma unroll
        for (int kc = 0; kc < 6; ++kc) pin4_(wfrag[jt][kc]);

    // ---- initial state: c0 = h0 = bc[u] + cond[b,:] @ Wc[:,u] ----
    float c_reg;
    {
        float a = bc[u];
        const float* cr = cond + b * kCOND;
#pragma unroll
        for (int kk = 0; kk < kCOND; ++kk) a = fmaf(cr[kk], Wc[kk * kU + u], a);
        c_reg = a;
        if (q == 0) hbuf[0][u] = (_Float16)a;
    }

    const float* xb = x + (size_t)b * kT * kD;

    // ---- stage chunk 0 (t = 0..15): 16x64 f32 -> f16, all 512 threads ----
    {
        const int row = tid >> 5;            // 0..15 (timestep within chunk)
        const int cp  = (tid & 31) * 2;      // f16 column pair
        float2 v = *(const float2*)&xb[(size_t)row * kD + cp];
        xs[0][row][cp]     = (_Float16)v.x;
        xs[0][row][cp + 1] = (_Float16)v.y;
    }

    float  h_out = 0.0f;
    float2 xpf   = make_float2(0.0f, 0.0f);  // in-flight chunk prefetch
    __syncthreads();

#pragma unroll 1
    for (int t = 0; t < kT; ++t) {
        const int cur  = t & 1;
        const int ring = (t >> 4) & 1;
        const int tin  = t & (kCH - 1);

        // issue next chunk's global loads (consumed 15 steps from now)
        if (tin == 0) {
            int tr = t + kCH + (tid >> 5);
            if (tr > kT - 1) tr = kT - 1;    // tail clamp: staged, never read
            xpf = *(const float2*)&xb[(size_t)tr * kD + (tid & 31) * 2];
        }

        // A-frags: broadcast reads (all 16 c-lanes in a quad read the same 16B)
        f16x8 af[6];
#pragma unroll
        for (int kc = 0; kc < 2; ++kc)       // x part, k = 32*kc + 8q + j
            af[kc] = *(const f16x8*)&xs[ring][tin][32 * kc + 8 * q];
#pragma unroll
        for (int kc = 2; kc < 6; ++kc)       // h part
            af[kc] = *(const f16x8*)&hbuf[cur][32 * (kc - 2) + 8 * q];

        // accumulators init to bias (row-constant C)
        f32x4 acc[4];
#pragma unroll
        for (int jt = 0; jt < 4; ++jt)
            acc[jt] = (f32x4){btile[jt], btile[jt], btile[jt], btile[jt]};

#pragma unroll
        for (int kc = 0; kc < 6; ++kc) {
#pragma unroll
            for (int jt = 0; jt < 4; ++jt)
                acc[jt] = __builtin_amdgcn_mfma_f32_16x16x32_f16(
                    af[kc], wfrag[jt][kc], acc[jt], 0, 0, 0);
        }

        // gates: D is row-constant -> reg 0 of each tile = G[16t + c]
        const float iv = sig_(acc[0][0]);
        const float fv = sig_(acc[1][0]);
        const float cb = tanh_(acc[2][0]);
        const float ov = sig_(acc[3][0]);
        c_reg = fmaf(fv, c_reg, iv * cb);
        h_out = ov * tanh_(c_reg);

        if (q == 0) hbuf[cur ^ 1][u] = (_Float16)h_out;   // h_{t+1}

        // end of chunk: convert + write the prefetched chunk into the ring
        if (tin == kCH - 1) {
            const int row = tid >> 5;
            const int cp  = (tid & 31) * 2;
            xs[ring ^ 1][row][cp]     = (_Float16)xpf.x;
            xs[ring ^ 1][row][cp + 1] = (_Float16)xpf.y;
        }

        // LDS-only barrier: do NOT drain vmcnt -> chunk prefetch stays in flight
        asm volatile("s_waitcnt lgkmcnt(0)\n\ts_barrier" ::: "memory");
    }

    if (q == 0) out[b * kU + u] = h_out;
}

extern "C" void kernel_launch(void* const* d_in, const int* in_sizes, int n_in,
                              void* d_out, int out_size, void* d_ws, size_t ws_size,
                              hipStream_t stream) {
    const float* x    = (const float*)d_in[0];
    const float* cond = (const float*)d_in[1];
    const float* Wc   = (const float*)d_in[2];
    const float* bc   = (const float*)d_in[3];
    const float* Wk   = (const float*)d_in[4];
    const float* Uk   = (const float*)d_in[5];
    const float* b    = (const float*)d_in[6];
    float* out = (float*)d_out;

    lstm_mfma<<<dim3(kB), dim3(512), 0, stream>>>(x, cond, Wc, bc, Wk, Uk, b, out);
}